// Round 1
// baseline (1119.573 us; speedup 1.0000x reference)
//
#include <hip/hip_runtime.h>

// VectorQuantizer: x[16,1024,16,16] f32, codebook[1,8192,1024], values[1,8192,1024]
// M=4096 tokens (b,n), d=1024, K=8192 codes.
// Round 0 baseline: fp32 tiled distance+argmin (VALU-bound, ~437us floor),
// then reduce + gather. Score = ||e||^2 - 2*t.e (||t||^2 constant per token).

constexpr int Dd = 1024;     // feature dim
constexpr int Nn = 256;      // H*W tokens per batch
constexpr int Bb = 16;       // batch
constexpr int Kk = 8192;     // codes
constexpr int Mm = Bb * Nn;  // 4096 tokens

constexpr int TM = 64;       // tokens per block
constexpr int TN = 64;       // codes per chunk
constexpr int DK = 32;       // k-slice per stage
constexpr int LDA = 68;      // padded LDS row (68*4B, 16B-aligned rows, breaks 64-stride conflicts)
constexpr int KSPLIT = 8;    // code-range splits (parallelism: 64 m-tiles x 8 = 512 blocks)
constexpr int KPER = Kk / KSPLIT;  // 1024 codes per block

// ---------------- e_sq: ||code||^2 per code ----------------
__global__ __launch_bounds__(256) void esq_kernel(const float* __restrict__ cb,
                                                  float* __restrict__ esq) {
    int wave = threadIdx.x >> 6, lane = threadIdx.x & 63;
    int k = blockIdx.x * 4 + wave;
    const float4* row = (const float4*)(cb + (size_t)k * Dd);
    float s = 0.f;
#pragma unroll
    for (int j = 0; j < 4; ++j) {
        float4 v = row[lane + 64 * j];
        s += v.x * v.x + v.y * v.y + v.z * v.z + v.w * v.w;
    }
#pragma unroll
    for (int off = 32; off; off >>= 1) s += __shfl_down(s, off, 64);
    if (lane == 0) esq[k] = s;
}

// ---------------- distance + per-split argmin ----------------
// grid: (Mm/TM, KSPLIT); block: 256 threads (16 tx over codes, 16 ty over tokens)
__global__ __launch_bounds__(256) void dist_kernel(const float* __restrict__ x,
                                                   const float* __restrict__ cb,
                                                   const float* __restrict__ esq,
                                                   float* __restrict__ pmin,
                                                   int* __restrict__ pidx) {
    __shared__ float As[DK][LDA];  // [k][token]
    __shared__ float Bs[DK][LDA];  // [k][code]
    __shared__ float rs[TM][16];
    __shared__ int ri[TM][16];

    const int tid = threadIdx.x;
    const int tx = tid & 15;   // code group
    const int ty = tid >> 4;   // token group
    const int bm = blockIdx.x;     // token tile 0..63
    const int split = blockIdx.y;  // 0..7
    const int b = bm >> 2;             // batch of this tile (64 tokens within one b)
    const int n0 = (bm & 3) * TM;      // n offset within batch
    const float* xb = x + (size_t)b * Dd * Nn + n0;
    const int k0 = split * KPER;

    float best[4];
    int bidx[4];
#pragma unroll
    for (int i = 0; i < 4; ++i) { best[i] = 1e30f; bidx[i] = 0; }

    for (int cc = 0; cc < KPER / TN; ++cc) {  // 16 code chunks
        const int nb = k0 + cc * TN;
        float acc[4][4];
#pragma unroll
        for (int i = 0; i < 4; ++i)
#pragma unroll
            for (int j = 0; j < 4; ++j) acc[i][j] = 0.f;

        for (int dc = 0; dc < Dd / DK; ++dc) {  // 32 k-slices
            const int d0 = dc * DK;
            // stage A: As[kk][tm] = x[b][d0+kk][n0+tm]; 512 float4, 2/thread
#pragma unroll
            for (int r = 0; r < 2; ++r) {
                int idx = tid + r * 256;
                int kk = idx >> 4;
                int c4 = idx & 15;
                float4 v = *(const float4*)(xb + (size_t)(d0 + kk) * Nn + c4 * 4);
                *(float4*)&As[kk][c4 * 4] = v;
            }
            // stage B (transpose): Bs[kk][tn] = cb[nb+tn][d0+kk]
#pragma unroll
            for (int r = 0; r < 2; ++r) {
                int idx = tid + r * 256;
                int code = idx >> 3;
                int c = idx & 7;
                float4 v = *(const float4*)(cb + (size_t)(nb + code) * Dd + d0 + c * 4);
                Bs[c * 4 + 0][code] = v.x;
                Bs[c * 4 + 1][code] = v.y;
                Bs[c * 4 + 2][code] = v.z;
                Bs[c * 4 + 3][code] = v.w;
            }
            __syncthreads();
#pragma unroll
            for (int kk = 0; kk < DK; ++kk) {
                const float4 a = *(const float4*)&As[kk][ty * 4];
                const float4 bv = *(const float4*)&Bs[kk][tx * 4];
                const float av[4] = {a.x, a.y, a.z, a.w};
                const float bw[4] = {bv.x, bv.y, bv.z, bv.w};
#pragma unroll
                for (int i = 0; i < 4; ++i)
#pragma unroll
                    for (int j = 0; j < 4; ++j)
                        acc[i][j] = fmaf(av[i], bw[j], acc[i][j]);
            }
            __syncthreads();
        }
        // score + running argmin (codes ascending per thread -> strict < keeps first occurrence)
#pragma unroll
        for (int j = 0; j < 4; ++j) {
            int code = nb + tx * 4 + j;
            float e = esq[code];
#pragma unroll
            for (int i = 0; i < 4; ++i) {
                float s = fmaf(-2.f, acc[i][j], e);
                if (s < best[i]) { best[i] = s; bidx[i] = code; }
            }
        }
    }
    // cross-thread (over tx) reduction per token
#pragma unroll
    for (int i = 0; i < 4; ++i) {
        rs[ty * 4 + i][tx] = best[i];
        ri[ty * 4 + i][tx] = bidx[i];
    }
    __syncthreads();
    if (tid < TM) {
        float bs = rs[tid][0];
        int bi = ri[tid][0];
#pragma unroll
        for (int j = 1; j < 16; ++j) {
            float s = rs[tid][j];
            int ii = ri[tid][j];
            if (s < bs || (s == bs && ii < bi)) { bs = s; bi = ii; }
        }
        int m = bm * TM + tid;
        pmin[split * Mm + m] = bs;
        pidx[split * Mm + m] = bi;
    }
}

// ---------------- reduce over splits ----------------
__global__ __launch_bounds__(256) void reduce_kernel(const float* __restrict__ pmin,
                                                     const int* __restrict__ pidx,
                                                     int* __restrict__ fidx) {
    int m = blockIdx.x * 256 + threadIdx.x;
    float bs = pmin[m];
    int bi = pidx[m];
#pragma unroll
    for (int s = 1; s < KSPLIT; ++s) {
        float v = pmin[(size_t)s * Mm + m];
        int ii = pidx[(size_t)s * Mm + m];
        if (v < bs || (v == bs && ii < bi)) { bs = v; bi = ii; }
    }
    fidx[m] = bi;
}

// ---------------- gather values -> out ----------------
// grid (Bb, Dd/64), block 256 (one thread per n). out[b][d][n] = values[idx[b,n]][d]
__global__ __launch_bounds__(256) void gather_kernel(const int* __restrict__ fidx,
                                                     const float* __restrict__ values,
                                                     float* __restrict__ out) {
    int n = threadIdx.x;
    int b = blockIdx.x;
    int dc = blockIdx.y;
    int row = fidx[b * Nn + n];
    const float* src = values + (size_t)row * Dd + dc * 64;
    float* dst = out + (size_t)b * Dd * Nn + (size_t)dc * 64 * Nn + n;
#pragma unroll
    for (int j = 0; j < 64; j += 4) {
        float4 v = *(const float4*)(src + j);
        dst[(j + 0) * Nn] = v.x;
        dst[(j + 1) * Nn] = v.y;
        dst[(j + 2) * Nn] = v.z;
        dst[(j + 3) * Nn] = v.w;
    }
}

extern "C" void kernel_launch(void* const* d_in, const int* in_sizes, int n_in,
                              void* d_out, int out_size, void* d_ws, size_t ws_size,
                              hipStream_t stream) {
    const float* x = (const float*)d_in[0];
    const float* cb = (const float*)d_in[1];
    const float* vals = (const float*)d_in[2];
    float* out = (float*)d_out;

    // ws layout (floats/ints, ~304 KB total)
    float* esq = (float*)d_ws;                 // [8192]
    float* pmin = esq + Kk;                    // [KSPLIT][Mm]
    int* pidx = (int*)(pmin + KSPLIT * Mm);    // [KSPLIT][Mm]
    int* fidx = pidx + KSPLIT * Mm;            // [Mm]

    esq_kernel<<<Kk / 4, 256, 0, stream>>>(cb, esq);
    dist_kernel<<<dim3(Mm / TM, KSPLIT), 256, 0, stream>>>(x, cb, esq, pmin, pidx);
    reduce_kernel<<<Mm / 256, 256, 0, stream>>>(pmin, pidx, fidx);
    gather_kernel<<<dim3(Bb, Dd / 64), 256, 0, stream>>>(fidx, vals, out);
}

// Round 2
// 286.946 us; speedup vs baseline: 3.9017x; 3.9017x over previous
//
#include <hip/hip_runtime.h>
#include <cstdint>

// VectorQuantizer: x[16,1024,16,16] f32, codebook[1,8192,1024], values[1,8192,1024]
// Round 2: bf16 MFMA candidate pass (m97-style 128x128 tile, global_load_lds w=16,
// swizzled LDS layout) + exact fp32 rescore of top-4 candidates per token.
// Argmin safety: top-2 per 64-code chunk, then global top-4, then exact rescore.

constexpr int Dd = 1024;   // feature dim (GEMM K)
constexpr int Nn = 256;    // tokens per batch
constexpr int Bb = 16;     // batch
constexpr int Kk = 8192;   // codes (GEMM N)
constexpr int Mm = 4096;   // tokens (GEMM M)
constexpr int BM = 128, BN = 128, BK = 32;
constexpr int NCHUNK = Kk / 64;  // 128 chunks of 64 codes

typedef __attribute__((ext_vector_type(8))) short bffrag;   // 8 bf16 = 4 VGPRs
typedef __attribute__((ext_vector_type(4))) float f32x4;
typedef unsigned long long u64;

__device__ __forceinline__ ushort f2bf(float f) {  // fp32 -> bf16 RNE
    uint32_t u = __float_as_uint(f);
    return (ushort)((u + 0x7FFFu + ((u >> 16) & 1u)) >> 16);
}

__device__ __forceinline__ void gload16(const void* g, void* l) {
    // async global->LDS, 16B/lane; LDS dest = wave-uniform base + lane*16
    __builtin_amdgcn_global_load_lds((const __attribute__((address_space(1))) uint32_t*)g,
                                     (__attribute__((address_space(3))) uint32_t*)l, 16, 0, 0);
}

// ---------- convert x [16][1024][256] f32 -> A [4096][1024] bf16 (transpose) ----------
// grid (16 b, 32 dchunk), 256 threads (one per n). Reads coalesced over n.
__global__ __launch_bounds__(256) void convx_kernel(const float* __restrict__ x,
                                                    ushort* __restrict__ A) {
    const int n = threadIdx.x, b = blockIdx.x, d0 = blockIdx.y * 32;
    const float* xb = x + (size_t)b * Dd * Nn + n;
    ushort* arow = A + (size_t)(b * Nn + n) * Dd + d0;
#pragma unroll
    for (int jj = 0; jj < 4; ++jj) {
        ushort tmp[8];
#pragma unroll
        for (int j = 0; j < 8; ++j) tmp[j] = f2bf(xb[(size_t)(d0 + jj * 8 + j) * Nn]);
        *(uint4*)&arow[jj * 8] = *(const uint4*)tmp;  // 16B store
    }
}

// ---------- convert cb -> B bf16 + exact fp32 ||e||^2 ----------
// grid 8192 (one block per code), 256 threads.
__global__ __launch_bounds__(256) void convcb_kernel(const float* __restrict__ cb,
                                                     ushort* __restrict__ Bm,
                                                     float* __restrict__ esq) {
    __shared__ float red[4];
    const int k = blockIdx.x, tid = threadIdx.x;
    float4 v = *(const float4*)&cb[(size_t)k * Dd + tid * 4];
    ushort4 o;
    o.x = f2bf(v.x); o.y = f2bf(v.y); o.z = f2bf(v.z); o.w = f2bf(v.w);
    *(ushort4*)&Bm[(size_t)k * Dd + tid * 4] = o;
    float ss = v.x * v.x + v.y * v.y + v.z * v.z + v.w * v.w;
#pragma unroll
    for (int off = 32; off; off >>= 1) ss += __shfl_down(ss, off, 64);
    if ((tid & 63) == 0) red[tid >> 6] = ss;
    __syncthreads();
    if (tid == 0) esq[k] = red[0] + red[1] + red[2] + red[3];
}

// ---------- MFMA distance + per-chunk top-2 candidates ----------
// grid (Kk/BN=64, Mm/BM=32); 256 threads = 4 waves in 2x2 (wm,wn), 64x64 each.
// LDS layout = fragment lane order: slot(g,l) holds row g*16+(l&15), k=(l>>4)*8..+7.
__global__ __launch_bounds__(256) void mfma_dist_kernel(const ushort* __restrict__ A,
                                                        const ushort* __restrict__ Bm,
                                                        const float* __restrict__ esq,
                                                        u64* __restrict__ cand) {
    __shared__ ushort As[4096];  // 8 groups * 64 lanes * 8 bf16 = 8KB
    __shared__ ushort Bs[4096];

    const int tid = threadIdx.x, lane = tid & 63, w = tid >> 6;
    const int wm = w >> 1, wn = w & 1;
    const int mBase = blockIdx.y * BM, nBase = blockIdx.x * BN;

    f32x4 acc[4][4];
#pragma unroll
    for (int i = 0; i < 4; ++i)
#pragma unroll
        for (int j = 0; j < 4; ++j) acc[i][j] = (f32x4)0.f;

    // staging source pointers: wave w stages groups 2w, 2w+1 of A and B
    const int g = 2 * w;
    const int r = lane & 15, q = lane >> 4;
    const ushort* gA0 = A + (size_t)(mBase + g * 16 + r) * Dd + q * 8;
    const ushort* gA1 = gA0 + (size_t)16 * Dd;
    const ushort* gB0 = Bm + (size_t)(nBase + g * 16 + r) * Dd + q * 8;
    const ushort* gB1 = gB0 + (size_t)16 * Dd;
    ushort* lA0 = &As[(g + 0) * 512];
    ushort* lA1 = &As[(g + 1) * 512];
    ushort* lB0 = &Bs[(g + 0) * 512];
    ushort* lB1 = &Bs[(g + 1) * 512];

    for (int dk = 0; dk < Dd; dk += BK) {
        __syncthreads();  // prior compute done before overwrite
        gload16(gA0, lA0);
        gload16(gA1, lA1);
        gload16(gB0, lB0);
        gload16(gB1, lB1);
        gA0 += BK; gA1 += BK; gB0 += BK; gB1 += BK;
        __syncthreads();  // drains vmcnt -> staged data visible
        bffrag af[4], bfr[4];
#pragma unroll
        for (int mi = 0; mi < 4; ++mi)
            af[mi] = *(const bffrag*)&As[((wm * 4 + mi) * 64 + lane) * 8];
#pragma unroll
        for (int ni = 0; ni < 4; ++ni)
            bfr[ni] = *(const bffrag*)&Bs[((wn * 4 + ni) * 64 + lane) * 8];
#pragma unroll
        for (int mi = 0; mi < 4; ++mi)
#pragma unroll
            for (int ni = 0; ni < 4; ++ni)
                acc[mi][ni] = __builtin_amdgcn_mfma_f32_16x16x32_bf16(
                    af[mi], bfr[ni], acc[mi][ni], 0, 0, 0);
    }

    // epilogue: score = esq - 2*cross, pack (monotone-score | code), top-2 per token
    // C/D layout: col(n) = lane&15, row(m) = (lane>>4)*4 + reg
    const int colcode = nBase + wn * 64 + (lane & 15);
    float e4[4];
#pragma unroll
    for (int ni = 0; ni < 4; ++ni) e4[ni] = esq[colcode + ni * 16];
    const int chunk = blockIdx.x * 2 + wn;

#pragma unroll
    for (int mi = 0; mi < 4; ++mi) {
#pragma unroll
        for (int reg = 0; reg < 4; ++reg) {
            u64 p[4];
#pragma unroll
            for (int ni = 0; ni < 4; ++ni) {
                float s = fmaf(-2.f, acc[mi][ni][reg], e4[ni]);
                uint32_t bb = __float_as_uint(s);
                uint32_t key = (bb & 0x80000000u) ? ~bb : (bb | 0x80000000u);
                p[ni] = ((u64)key << 32) | (uint32_t)(colcode + ni * 16);
            }
            u64 l01 = p[0] < p[1] ? p[0] : p[1], h01 = p[0] < p[1] ? p[1] : p[0];
            u64 l23 = p[2] < p[3] ? p[2] : p[3], h23 = p[2] < p[3] ? p[3] : p[2];
            u64 t1 = l01 < l23 ? l01 : l23;
            u64 hm = l01 < l23 ? l23 : l01;
            u64 lm = h01 < h23 ? h01 : h23;
            u64 t2 = hm < lm ? hm : lm;
#pragma unroll
            for (int d = 1; d < 16; d <<= 1) {  // butterfly within 16-lane group
                u64 o1 = __shfl_xor(t1, d, 64);
                u64 o2 = __shfl_xor(t2, d, 64);
                u64 hi = t1 < o1 ? o1 : t1;
                t1 = t1 < o1 ? t1 : o1;
                u64 m2 = t2 < o2 ? t2 : o2;
                t2 = hi < m2 ? hi : m2;
            }
            if ((lane & 15) == 0) {
                int t = mBase + wm * 64 + mi * 16 + (lane >> 4) * 4 + reg;
                cand[((size_t)t * NCHUNK + chunk) * 2 + 0] = t1;
                cand[((size_t)t * NCHUNK + chunk) * 2 + 1] = t2;
            }
        }
    }
}

// ---------- merge 256 candidates/token -> approx top-4 ----------
// grid 4096 (one wave per token).
__global__ __launch_bounds__(64) void select_kernel(const u64* __restrict__ cand,
                                                    int* __restrict__ cand4) {
    const int t = blockIdx.x, lane = threadIdx.x;
    u64 v[4];
#pragma unroll
    for (int j = 0; j < 4; ++j) v[j] = cand[(size_t)t * 256 + lane * 4 + j];
#pragma unroll
    for (int rd = 0; rd < 4; ++rd) {
        u64 loc = v[0] < v[1] ? v[0] : v[1];
        u64 l2 = v[2] < v[3] ? v[2] : v[3];
        loc = loc < l2 ? loc : l2;
#pragma unroll
        for (int d = 32; d; d >>= 1) {
            u64 o = __shfl_xor(loc, d, 64);
            loc = loc < o ? loc : o;
        }
        if (lane == 0) cand4[t * 4 + rd] = (int)(uint32_t)loc;
#pragma unroll
        for (int j = 0; j < 4; ++j)
            if (v[j] == loc) v[j] = ~0ULL;  // exclude (packed values unique)
    }
}

// ---------- exact fp32 rescore of 4 candidates ----------
// grid 4096 (one block per token), 256 threads; thread handles d = tid*4..+3.
__global__ __launch_bounds__(256) void rescore_kernel(const float* __restrict__ x,
                                                      const float* __restrict__ cb,
                                                      const float* __restrict__ esq,
                                                      const int* __restrict__ cand4,
                                                      int* __restrict__ fidx) {
    __shared__ float red[4][4];  // [wave][cand]
    const int t = blockIdx.x, tid = threadIdx.x;
    const int b = t >> 8, n = t & 255;
    int c[4];
#pragma unroll
    for (int j = 0; j < 4; ++j) c[j] = cand4[t * 4 + j];
    const float* xb = x + (size_t)b * Dd * Nn + n;
    float xv[4];
#pragma unroll
    for (int j = 0; j < 4; ++j) xv[j] = xb[(size_t)(tid * 4 + j) * Nn];
    float part[4];
#pragma unroll
    for (int cc = 0; cc < 4; ++cc) {
        float4 wv = *(const float4*)&cb[(size_t)c[cc] * Dd + tid * 4];
        part[cc] = xv[0] * wv.x + xv[1] * wv.y + xv[2] * wv.z + xv[3] * wv.w;
    }
#pragma unroll
    for (int cc = 0; cc < 4; ++cc)
#pragma unroll
        for (int off = 32; off; off >>= 1) part[cc] += __shfl_down(part[cc], off, 64);
    if ((tid & 63) == 0)
#pragma unroll
        for (int cc = 0; cc < 4; ++cc) red[tid >> 6][cc] = part[cc];
    __syncthreads();
    if (tid == 0) {
        float bs = 1e30f;
        int bi = 0x7FFFFFFF;
#pragma unroll
        for (int cc = 0; cc < 4; ++cc) {
            float cross = red[0][cc] + red[1][cc] + red[2][cc] + red[3][cc];
            float s = fmaf(-2.f, cross, esq[c[cc]]);
            if (s < bs || (s == bs && c[cc] < bi)) { bs = s; bi = c[cc]; }
        }
        fidx[t] = bi;
    }
}

// ---------- gather values -> out ----------
__global__ __launch_bounds__(256) void gather_kernel(const int* __restrict__ fidx,
                                                     const float* __restrict__ values,
                                                     float* __restrict__ out) {
    const int n = threadIdx.x, b = blockIdx.x, dc = blockIdx.y;
    const int row = fidx[b * Nn + n];
    const float* src = values + (size_t)row * Dd + dc * 64;
    float* dst = out + (size_t)b * Dd * Nn + (size_t)dc * 64 * Nn + n;
#pragma unroll
    for (int j = 0; j < 64; j += 4) {
        float4 v = *(const float4*)(src + j);
        dst[(j + 0) * Nn] = v.x;
        dst[(j + 1) * Nn] = v.y;
        dst[(j + 2) * Nn] = v.z;
        dst[(j + 3) * Nn] = v.w;
    }
}

extern "C" void kernel_launch(void* const* d_in, const int* in_sizes, int n_in,
                              void* d_out, int out_size, void* d_ws, size_t ws_size,
                              hipStream_t stream) {
    const float* x = (const float*)d_in[0];
    const float* cb = (const float*)d_in[1];
    const float* vals = (const float*)d_in[2];
    float* out = (float*)d_out;

    // ws layout (~32.1 MB)
    char* p = (char*)d_ws;
    ushort* Abf = (ushort*)p;                    p += (size_t)Mm * Dd * 2;        // 8 MB
    ushort* Bbf = (ushort*)p;                    p += (size_t)Kk * Dd * 2;        // 16 MB
    float* esq = (float*)p;                      p += (size_t)Kk * 4;             // 32 KB
    u64* cand = (u64*)p;                         p += (size_t)Mm * NCHUNK * 2 * 8;// 8 MB
    int* cand4 = (int*)p;                        p += (size_t)Mm * 4 * 4;         // 64 KB
    int* fidx = (int*)p;                                                           // 16 KB

    convx_kernel<<<dim3(Bb, 32), 256, 0, stream>>>(x, Abf);
    convcb_kernel<<<Kk, 256, 0, stream>>>(cb, Bbf, esq);
    mfma_dist_kernel<<<dim3(Kk / BN, Mm / BM), 256, 0, stream>>>(Abf, Bbf, esq, cand);
    select_kernel<<<Mm, 64, 0, stream>>>(cand, cand4);
    rescore_kernel<<<Mm, 256, 0, stream>>>(x, cb, esq, cand4, fidx);
    gather_kernel<<<dim3(Bb, Dd / 64), 256, 0, stream>>>(fidx, vals, out);
}

// Round 3
// 275.484 us; speedup vs baseline: 4.0640x; 1.0416x over previous
//
#include <hip/hip_runtime.h>
#include <cstdint>

// VectorQuantizer: x[16,1024,16,16] f32, codebook[1,8192,1024], values[1,8192,1024]
// Round 3: bf16 MFMA candidate pass, waves = 32 rows x 128 cols (chunk=128,
// 8 epilogue sequences/wave, raw-float-bits u64 keys), + fp32 xT for coalesced
// exact rescore of top-4 candidates.

constexpr int Dd = 1024;   // feature dim (GEMM K)
constexpr int Nn = 256;    // tokens per batch
constexpr int Bb = 16;     // batch
constexpr int Kk = 8192;   // codes (GEMM N)
constexpr int Mm = 4096;   // tokens (GEMM M)
constexpr int BM = 128, BN = 128, BK = 32;
constexpr int NCHUNK = Kk / 128;  // 64 chunks of 128 codes

typedef __attribute__((ext_vector_type(8))) short bffrag;   // 8 bf16 = 4 VGPRs
typedef __attribute__((ext_vector_type(4))) float f32x4;
typedef unsigned long long u64;

__device__ __forceinline__ ushort f2bf(float f) {  // fp32 -> bf16 RNE
    uint32_t u = __float_as_uint(f);
    return (ushort)((u + 0x7FFFu + ((u >> 16) & 1u)) >> 16);
}

__device__ __forceinline__ void gload16(const void* g, void* l) {
    __builtin_amdgcn_global_load_lds((const __attribute__((address_space(1))) uint32_t*)g,
                                     (__attribute__((address_space(3))) uint32_t*)l, 16, 0, 0);
}

// sort pair ascending
__device__ __forceinline__ void mm2(u64& a, u64& b) {
    u64 lo = a < b ? a : b;
    u64 hi = a < b ? b : a;
    a = lo; b = hi;
}
// merge two sorted pairs -> top-2 of union in (a1,a2)
__device__ __forceinline__ void merge2(u64& a1, u64& a2, u64 b1, u64 b2) {
    u64 t1 = a1 < b1 ? a1 : b1;
    u64 hi = a1 < b1 ? b1 : a1;
    u64 l2 = a2 < b2 ? a2 : b2;
    a2 = hi < l2 ? hi : l2;
    a1 = t1;
}

// ---------- convert x [16][1024][256] f32 -> A [4096][1024] bf16 (transpose) ----------
__global__ __launch_bounds__(256) void convx_kernel(const float* __restrict__ x,
                                                    ushort* __restrict__ A) {
    const int n = threadIdx.x, b = blockIdx.x, d0 = blockIdx.y * 32;
    const float* xb = x + (size_t)b * Dd * Nn + n;
    ushort* arow = A + (size_t)(b * Nn + n) * Dd + d0;
#pragma unroll
    for (int jj = 0; jj < 4; ++jj) {
        ushort tmp[8];
#pragma unroll
        for (int j = 0; j < 8; ++j) tmp[j] = f2bf(xb[(size_t)(d0 + jj * 8 + j) * Nn]);
        *(uint4*)&arow[jj * 8] = *(const uint4*)tmp;
    }
}

// ---------- x -> xT fp32 [4096][1024] (runs AFTER dist; aliases Abf/Bbf region) ----------
__global__ __launch_bounds__(256) void transx_kernel(const float* __restrict__ x,
                                                     float* __restrict__ xT) {
    const int n = threadIdx.x, b = blockIdx.x, d0 = blockIdx.y * 32;
    const float* xb = x + (size_t)b * Dd * Nn + n;
    float* row = xT + (size_t)(b * Nn + n) * Dd + d0;
#pragma unroll
    for (int jj = 0; jj < 8; ++jj) {
        float4 v;
        v.x = xb[(size_t)(d0 + jj * 4 + 0) * Nn];
        v.y = xb[(size_t)(d0 + jj * 4 + 1) * Nn];
        v.z = xb[(size_t)(d0 + jj * 4 + 2) * Nn];
        v.w = xb[(size_t)(d0 + jj * 4 + 3) * Nn];
        *(float4*)&row[jj * 4] = v;
    }
}

// ---------- convert cb -> B bf16 + exact fp32 ||e||^2 ----------
__global__ __launch_bounds__(256) void convcb_kernel(const float* __restrict__ cb,
                                                     ushort* __restrict__ Bm,
                                                     float* __restrict__ esq) {
    __shared__ float red[4];
    const int k = blockIdx.x, tid = threadIdx.x;
    float4 v = *(const float4*)&cb[(size_t)k * Dd + tid * 4];
    ushort4 o;
    o.x = f2bf(v.x); o.y = f2bf(v.y); o.z = f2bf(v.z); o.w = f2bf(v.w);
    *(ushort4*)&Bm[(size_t)k * Dd + tid * 4] = o;
    float ss = v.x * v.x + v.y * v.y + v.z * v.z + v.w * v.w;
#pragma unroll
    for (int off = 32; off; off >>= 1) ss += __shfl_down(ss, off, 64);
    if ((tid & 63) == 0) red[tid >> 6] = ss;
    __syncthreads();
    if (tid == 0) esq[k] = red[0] + red[1] + red[2] + red[3];
}

// ---------- MFMA distance + per-128-chunk top-2 candidates ----------
// grid (Kk/BN=64, Mm/BM=32); 4 waves, wave w owns rows w*32..w*32+31 x all 128 cols.
__global__ __launch_bounds__(256) void mfma_dist_kernel(const ushort* __restrict__ A,
                                                        const ushort* __restrict__ Bm,
                                                        const float* __restrict__ esq,
                                                        u64* __restrict__ cand) {
    __shared__ ushort As[4096];  // 8 groups * 64 lanes * 8 bf16 = 8KB
    __shared__ ushort Bs[4096];

    const int tid = threadIdx.x, lane = tid & 63, w = tid >> 6;
    const int mBase = blockIdx.y * BM, nBase = blockIdx.x * BN;

    f32x4 acc[2][8];
#pragma unroll
    for (int i = 0; i < 2; ++i)
#pragma unroll
        for (int j = 0; j < 8; ++j) acc[i][j] = (f32x4)0.f;

    // staging: wave w stages groups 2w, 2w+1 of both A and B (unchanged from r2)
    const int g = 2 * w;
    const int r = lane & 15, q = lane >> 4;
    const ushort* gA0 = A + (size_t)(mBase + g * 16 + r) * Dd + q * 8;
    const ushort* gA1 = gA0 + (size_t)16 * Dd;
    const ushort* gB0 = Bm + (size_t)(nBase + g * 16 + r) * Dd + q * 8;
    const ushort* gB1 = gB0 + (size_t)16 * Dd;
    ushort* lA0 = &As[(g + 0) * 512];
    ushort* lA1 = &As[(g + 1) * 512];
    ushort* lB0 = &Bs[(g + 0) * 512];
    ushort* lB1 = &Bs[(g + 1) * 512];

    for (int dk = 0; dk < Dd; dk += BK) {
        __syncthreads();
        gload16(gA0, lA0);
        gload16(gA1, lA1);
        gload16(gB0, lB0);
        gload16(gB1, lB1);
        gA0 += BK; gA1 += BK; gB0 += BK; gB1 += BK;
        __syncthreads();
        bffrag af[2], bfr[8];
#pragma unroll
        for (int mi = 0; mi < 2; ++mi)
            af[mi] = *(const bffrag*)&As[((2 * w + mi) * 64 + lane) * 8];
#pragma unroll
        for (int ni = 0; ni < 8; ++ni)
            bfr[ni] = *(const bffrag*)&Bs[(ni * 64 + lane) * 8];
#pragma unroll
        for (int mi = 0; mi < 2; ++mi)
#pragma unroll
            for (int ni = 0; ni < 8; ++ni)
                acc[mi][ni] = __builtin_amdgcn_mfma_f32_16x16x32_bf16(
                    af[mi], bfr[ni], acc[mi][ni], 0, 0, 0);
    }

    // epilogue. C/D layout: col = lane&15 (+ni*16), row = (lane>>4)*4 + reg.
    // score = max(esq - 2*cross, 0) >= 0 -> raw float bits are the sort key.
    uint32_t colc[8];
    float e8[8];
#pragma unroll
    for (int ni = 0; ni < 8; ++ni) {
        colc[ni] = (uint32_t)(nBase + ni * 16 + (lane & 15));
        e8[ni] = esq[colc[ni]];
    }
    const int chunk = blockIdx.x;

#pragma unroll
    for (int mi = 0; mi < 2; ++mi) {
#pragma unroll
        for (int reg = 0; reg < 4; ++reg) {
            u64 p[8];
#pragma unroll
            for (int ni = 0; ni < 8; ++ni) {
                float s = fmaxf(fmaf(-2.f, acc[mi][ni][reg], e8[ni]), 0.f);
                p[ni] = ((u64)__float_as_uint(s) << 32) | colc[ni];
            }
            mm2(p[0], p[1]); mm2(p[2], p[3]); mm2(p[4], p[5]); mm2(p[6], p[7]);
            merge2(p[0], p[1], p[2], p[3]);
            merge2(p[4], p[5], p[6], p[7]);
            merge2(p[0], p[1], p[4], p[5]);
            u64 t1 = p[0], t2 = p[1];
#pragma unroll
            for (int d = 1; d < 16; d <<= 1) {
                u64 o1 = __shfl_xor(t1, d, 64);
                u64 o2 = __shfl_xor(t2, d, 64);
                merge2(t1, t2, o1, o2);
            }
            if ((lane & 15) == 0) {
                int t = mBase + w * 32 + mi * 16 + (lane >> 4) * 4 + reg;
                cand[((size_t)t * NCHUNK + chunk) * 2 + 0] = t1;
                cand[((size_t)t * NCHUNK + chunk) * 2 + 1] = t2;
            }
        }
    }
}

// ---------- merge 128 candidates/token -> approx top-4 ----------
// 256-thread blocks, 4 tokens each (one wave per token).
__global__ __launch_bounds__(256) void select_kernel(const u64* __restrict__ cand,
                                                     int* __restrict__ cand4) {
    const int t = blockIdx.x * 4 + (threadIdx.x >> 6), lane = threadIdx.x & 63;
    u64 v[2];
#pragma unroll
    for (int j = 0; j < 2; ++j) v[j] = cand[(size_t)t * (NCHUNK * 2) + lane * 2 + j];
#pragma unroll
    for (int rd = 0; rd < 4; ++rd) {
        u64 loc = v[0] < v[1] ? v[0] : v[1];
#pragma unroll
        for (int d = 32; d; d >>= 1) {
            u64 o = __shfl_xor(loc, d, 64);
            loc = loc < o ? loc : o;
        }
        if (lane == 0) cand4[t * 4 + rd] = (int)(uint32_t)loc;
#pragma unroll
        for (int j = 0; j < 2; ++j)
            if (v[j] == loc) v[j] = ~0ULL;  // packed values unique per token
    }
}

// ---------- exact fp32 rescore of 4 candidates (coalesced via xT) ----------
__global__ __launch_bounds__(256) void rescore_kernel(const float* __restrict__ xT,
                                                      const float* __restrict__ cb,
                                                      const float* __restrict__ esq,
                                                      const int* __restrict__ cand4,
                                                      int* __restrict__ fidx) {
    __shared__ float red[4][4];  // [wave][cand]
    const int t = blockIdx.x, tid = threadIdx.x;
    int c[4];
#pragma unroll
    for (int j = 0; j < 4; ++j) c[j] = cand4[t * 4 + j];
    float4 xv = *(const float4*)&xT[(size_t)t * Dd + tid * 4];
    float part[4];
#pragma unroll
    for (int cc = 0; cc < 4; ++cc) {
        float4 wv = *(const float4*)&cb[(size_t)c[cc] * Dd + tid * 4];
        part[cc] = xv.x * wv.x + xv.y * wv.y + xv.z * wv.z + xv.w * wv.w;
    }
#pragma unroll
    for (int cc = 0; cc < 4; ++cc)
#pragma unroll
        for (int off = 32; off; off >>= 1) part[cc] += __shfl_down(part[cc], off, 64);
    if ((tid & 63) == 0)
#pragma unroll
        for (int cc = 0; cc < 4; ++cc) red[tid >> 6][cc] = part[cc];
    __syncthreads();
    if (tid == 0) {
        float bs = 1e30f;
        int bi = 0x7FFFFFFF;
#pragma unroll
        for (int cc = 0; cc < 4; ++cc) {
            float cross = red[0][cc] + red[1][cc] + red[2][cc] + red[3][cc];
            float s = fmaf(-2.f, cross, esq[c[cc]]);
            if (s < bs || (s == bs && c[cc] < bi)) { bs = s; bi = c[cc]; }
        }
        fidx[t] = bi;
    }
}

// ---------- gather values -> out ----------
__global__ __launch_bounds__(256) void gather_kernel(const int* __restrict__ fidx,
                                                     const float* __restrict__ values,
                                                     float* __restrict__ out) {
    const int n = threadIdx.x, b = blockIdx.x, dc = blockIdx.y;
    const int row = fidx[b * Nn + n];
    const float* src = values + (size_t)row * Dd + dc * 64;
    float* dst = out + (size_t)b * Dd * Nn + (size_t)dc * 64 * Nn + n;
#pragma unroll
    for (int j = 0; j < 64; j += 4) {
        float4 v = *(const float4*)(src + j);
        dst[(j + 0) * Nn] = v.x;
        dst[(j + 1) * Nn] = v.y;
        dst[(j + 2) * Nn] = v.z;
        dst[(j + 3) * Nn] = v.w;
    }
}

extern "C" void kernel_launch(void* const* d_in, const int* in_sizes, int n_in,
                              void* d_out, int out_size, void* d_ws, size_t ws_size,
                              hipStream_t stream) {
    const float* x = (const float*)d_in[0];
    const float* cb = (const float*)d_in[1];
    const float* vals = (const float*)d_in[2];
    float* out = (float*)d_out;

    // ws layout (~28.2 MB). xT (16 MB) aliases Abf+Bbf, which are dead after dist.
    char* p = (char*)d_ws;
    ushort* Abf = (ushort*)p;                    p += (size_t)Mm * Dd * 2;          // 8 MB
    ushort* Bbf = (ushort*)p;                    p += (size_t)Kk * Dd * 2;          // 16 MB
    float* esq = (float*)p;                      p += (size_t)Kk * 4;               // 32 KB
    u64* cand = (u64*)p;                         p += (size_t)Mm * NCHUNK * 2 * 8;  // 4 MB
    int* cand4 = (int*)p;                        p += (size_t)Mm * 4 * 4;           // 64 KB
    int* fidx = (int*)p;                                                            // 16 KB
    float* xT = (float*)d_ws;  // [4096][1024] fp32, reuses first 16 MB

    convx_kernel<<<dim3(Bb, 32), 256, 0, stream>>>(x, Abf);
    convcb_kernel<<<Kk, 256, 0, stream>>>(cb, Bbf, esq);
    mfma_dist_kernel<<<dim3(Kk / BN, Mm / BM), 256, 0, stream>>>(Abf, Bbf, esq, cand);
    transx_kernel<<<dim3(Bb, 32), 256, 0, stream>>>(x, xT);
    select_kernel<<<Mm / 4, 256, 0, stream>>>(cand, cand4);
    rescore_kernel<<<Mm, 256, 0, stream>>>(xT, cb, esq, cand4, fidx);
    gather_kernel<<<dim3(Bb, Dd / 64), 256, 0, stream>>>(fidx, vals, out);
}